// Round 2
// baseline (98.396 us; speedup 1.0000x reference)
//
#include <hip/hip_runtime.h>
#include <math.h>

#define NN  8192
#define DD  128
#define CLS 16
#define ALPHA 0.2f

// ---------------------------------------------------------------------------
// Probe: decide adjacency encoding.
//   byte-bool: adj[i*(NN+1)] == 1 for every i (self loops).
//   int32 0/1: byte offset i*8193 with i%4!=0 is an upper byte of a 0/1 word
//              -> always 0.
// flag=1 -> byte encoding, flag=0 -> int32 encoding.
// ---------------------------------------------------------------------------
__global__ void adj_probe(const unsigned char* __restrict__ adj, int* flag)
{
    if (threadIdx.x == 0 && blockIdx.x == 0) {
        int cnt = 0;
        for (int i = 1; i < 33; ++i)
            if ((i & 3) != 0)
                cnt += (adj[(size_t)i * (NN + 1)] != 0) ? 1 : 0;
        *flag = (cnt > 12) ? 1 : 0;
    }
}

// ---------------------------------------------------------------------------
// Kernel 1: per-row feature transform.
//   h[i] = (artanh(||x_i||)/||x_i||) * x_i @ W + b        [N,16]
//   s[i] = h[i].a_src ;  dv[i] = h[i].a_dst
// One wave per row; 4 rows per 256-thread block.
// ---------------------------------------------------------------------------
__global__ __launch_bounds__(256) void hat_feat(
    const float* __restrict__ x, const float* __restrict__ W,
    const float* __restrict__ b, const float* __restrict__ a_src,
    const float* __restrict__ a_dst,
    float* __restrict__ h, float* __restrict__ s, float* __restrict__ dv)
{
    const int lane = threadIdx.x & 63;
    const int row  = (blockIdx.x << 2) + (threadIdx.x >> 6);

    const float* xr = x + (size_t)row * DD;
    float x0 = xr[lane];
    float x1 = xr[lane + 64];

    float nsq = x0 * x0 + x1 * x1;
    #pragma unroll
    for (int o = 32; o > 0; o >>= 1) nsq += __shfl_xor(nsq, o);

    float norm = fmaxf(sqrtf(nsq), 1e-15f);
    float t    = fminf(norm, 1.0f - 1e-7f);
    float art  = 0.5f * (log1pf(t) - log1pf(-t));
    float scl  = art / norm;
    x0 *= scl;
    x1 *= scl;

    float hc[CLS];
    #pragma unroll
    for (int c = 0; c < CLS; ++c)
        hc[c] = x0 * W[lane * CLS + c] + x1 * W[(lane + 64) * CLS + c];

    #pragma unroll
    for (int o = 32; o > 0; o >>= 1) {
        #pragma unroll
        for (int c = 0; c < CLS; ++c) hc[c] += __shfl_xor(hc[c], o);
    }

    float sv = 0.0f, dvv = 0.0f;
    #pragma unroll
    for (int c = 0; c < CLS; ++c) {
        hc[c] += b[c];
        sv  += hc[c] * a_src[c];
        dvv += hc[c] * a_dst[c];
    }

    if (lane == 0) {
        float* hr = h + (size_t)row * CLS;
        #pragma unroll
        for (int c = 0; c < CLS; ++c) hr[c] = hc[c];
        s[row]  = sv;
        dv[row] = dvv;
    }
}

// ---------------------------------------------------------------------------
// Kernel 2: masked row-softmax attention + aggregate + elu + expmap0 + proj.
// One wave per row. Handles byte-bool or int32 adjacency via *flag.
// ---------------------------------------------------------------------------
__global__ __launch_bounds__(256) void hat_attn(
    const float* __restrict__ h, const float* __restrict__ s,
    const float* __restrict__ dv, const unsigned char* __restrict__ adj,
    const int* __restrict__ flag, float* __restrict__ out)
{
    const int lane = threadIdx.x & 63;
    const int row  = (blockIdx.x << 2) + (threadIdx.x >> 6);

    const float si = s[row];
    float m = -3.0e38f, l = 0.0f;
    float acc[CLS];
    #pragma unroll
    for (int c = 0; c < CLS; ++c) acc[c] = 0.0f;

    auto hit = [&](int j) {
        float e = si + dv[j];
        e = (e > 0.0f) ? e : ALPHA * e;                 // LeakyReLU
        float mn = fmaxf(m, e);
        float sc = __expf(m - mn);
        float w  = __expf(e - mn);
        l = l * sc + w;
        const float* hj = h + (size_t)j * CLS;
        #pragma unroll
        for (int c = 0; c < CLS; ++c)
            acc[c] = acc[c] * sc + w * hj[c];
        m = mn;
    };

    if (*flag) {
        // ---- byte-bool encoding: row = NN bytes ----
        const uint4* arow = reinterpret_cast<const uint4*>(adj + (size_t)row * NN);
        auto procw = [&](unsigned int v, int jbase) {
            if (v == 0u) return;
            #pragma unroll
            for (int bb = 0; bb < 4; ++bb)
                if (v & (0xffu << (bb * 8))) hit(jbase + bb);
        };
        #pragma unroll
        for (int it = 0; it < NN / 16 / 64; ++it) {     // 8 iters
            const int u  = lane + (it << 6);
            const uint4 a = arow[u];
            const int jb = u << 4;
            procw(a.x, jb); procw(a.y, jb + 4);
            procw(a.z, jb + 8); procw(a.w, jb + 12);
        }
    } else {
        // ---- int32 0/1 encoding: row = NN ints ----
        const uint4* arow = reinterpret_cast<const uint4*>(
            reinterpret_cast<const int*>(adj) + (size_t)row * NN);
        for (int it = 0; it < NN / 4 / 64; ++it) {      // 32 iters
            const int u  = lane + (it << 6);
            const uint4 a = arow[u];
            const int jb = u << 2;
            if (a.x) hit(jb);
            if (a.y) hit(jb + 1);
            if (a.z) hit(jb + 2);
            if (a.w) hit(jb + 3);
        }
    }

    // 64-lane butterfly merge of online-softmax states
    #pragma unroll
    for (int o = 32; o > 0; o >>= 1) {
        float mo = __shfl_xor(m, o);
        float lo = __shfl_xor(l, o);
        float mn = fmaxf(m, mo);
        float sa = __expf(m  - mn);
        float sb = __expf(mo - mn);
        l = l * sa + lo * sb;
        #pragma unroll
        for (int c = 0; c < CLS; ++c) {
            float ao = __shfl_xor(acc[c], o);
            acc[c] = acc[c] * sa + ao * sb;
        }
        m = mn;
    }

    if (lane == 0) {
        float* orow = out + (size_t)row * CLS;
        if (l > 0.0f) {
            const float inv_l = 1.0f / l;
            float u[CLS];
            float nsq = 0.0f;
            #pragma unroll
            for (int c = 0; c < CLS; ++c) {
                float v = acc[c] * inv_l;
                v = (v > 0.0f) ? v : expm1f(v);         // elu
                u[c] = v;
                nsq += v * v;
            }
            float norm = fmaxf(sqrtf(nsq), 1e-15f);
            float th   = tanhf(norm);
            float sc2  = th / norm;                      // expmap0 scale
            const float maxnorm = 1.0f - 1e-5f;          // proj (c=1)
            float sc3  = (th > maxnorm) ? (maxnorm / th) : 1.0f;
            #pragma unroll
            for (int c = 0; c < CLS; ++c) orow[c] = u[c] * sc2 * sc3;
        } else {
            #pragma unroll
            for (int c = 0; c < CLS; ++c) orow[c] = 0.0f;
        }
    }
}

// ---------------------------------------------------------------------------
extern "C" void kernel_launch(void* const* d_in, const int* in_sizes, int n_in,
                              void* d_out, int out_size, void* d_ws, size_t ws_size,
                              hipStream_t stream) {
    const float*         x     = (const float*)d_in[0];
    const unsigned char* adj   = (const unsigned char*)d_in[1];
    const float*         W     = (const float*)d_in[2];
    const float*         b     = (const float*)d_in[3];
    const float*         a_src = (const float*)d_in[4];
    const float*         a_dst = (const float*)d_in[5];
    float*               out   = (float*)d_out;

    float* h    = (float*)d_ws;               // [NN, CLS]
    float* s    = h + (size_t)NN * CLS;       // [NN]
    float* dv   = s + NN;                     // [NN]
    int*   flag = (int*)(dv + NN);

    adj_probe<<<1, 64, 0, stream>>>(adj, flag);
    hat_feat<<<NN / 4, 256, 0, stream>>>(x, W, b, a_src, a_dst, h, s, dv);
    hat_attn<<<NN / 4, 256, 0, stream>>>(h, s, dv, adj, flag, out);
}

// Round 3
// 67.252 us; speedup vs baseline: 1.4631x; 1.4631x over previous
//
#include <hip/hip_runtime.h>
#include <math.h>

#define NN  8192
#define DD  128
#define CLS 16
#define ALPHA 0.2f

// ---------------------------------------------------------------------------
// Probe: decide adjacency encoding (byte-bool vs int32 0/1), parallel.
//   byte-bool: adj[i*(NN+1)] != 0 for all i (self loops).
//   int32:     byte offset i*8193 with i%4!=0 is an upper byte of 0/1 -> 0.
// ---------------------------------------------------------------------------
__global__ void adj_probe(const unsigned char* __restrict__ adj, int* flag)
{
    const int lane = threadIdx.x & 63;
    const int i = lane + 1;                         // rows 1..64
    const int ok = ((i & 3) != 0) && (adj[(size_t)i * (NN + 1)] != 0);
    unsigned long long b = __ballot(ok);
    if (threadIdx.x == 0) *flag = (__popcll(b) > 24) ? 1 : 0;
}

// ---------------------------------------------------------------------------
// Kernel 1: per-row feature transform (unchanged, verified).
//   h[i] = (artanh(||x_i||)/||x_i||) * x_i @ W + b ; s=h.a_src ; dv=h.a_dst
// ---------------------------------------------------------------------------
__global__ __launch_bounds__(256) void hat_feat(
    const float* __restrict__ x, const float* __restrict__ W,
    const float* __restrict__ b, const float* __restrict__ a_src,
    const float* __restrict__ a_dst,
    float* __restrict__ h, float* __restrict__ s, float* __restrict__ dv)
{
    const int lane = threadIdx.x & 63;
    const int row  = (blockIdx.x << 2) + (threadIdx.x >> 6);

    const float* xr = x + (size_t)row * DD;
    float x0 = xr[lane];
    float x1 = xr[lane + 64];

    float nsq = x0 * x0 + x1 * x1;
    #pragma unroll
    for (int o = 32; o > 0; o >>= 1) nsq += __shfl_xor(nsq, o);

    float norm = fmaxf(sqrtf(nsq), 1e-15f);
    float t    = fminf(norm, 1.0f - 1e-7f);
    float art  = 0.5f * (log1pf(t) - log1pf(-t));
    float scl  = art / norm;
    x0 *= scl;
    x1 *= scl;

    float hc[CLS];
    #pragma unroll
    for (int c = 0; c < CLS; ++c)
        hc[c] = x0 * W[lane * CLS + c] + x1 * W[(lane + 64) * CLS + c];

    #pragma unroll
    for (int o = 32; o > 0; o >>= 1) {
        #pragma unroll
        for (int c = 0; c < CLS; ++c) hc[c] += __shfl_xor(hc[c], o);
    }

    float sv = 0.0f, dvv = 0.0f;
    #pragma unroll
    for (int c = 0; c < CLS; ++c) {
        hc[c] += b[c];
        sv  += hc[c] * a_src[c];
        dvv += hc[c] * a_dst[c];
    }

    if (lane == 0) {
        float* hr = h + (size_t)row * CLS;
        #pragma unroll
        for (int c = 0; c < CLS; ++c) hr[c] = hc[c];
        s[row]  = sv;
        dv[row] = dvv;
    }
}

// ---------------------------------------------------------------------------
// Kernel 2: ballot-scan attention. One wave per row.
// Coalesced mask scan -> per-lane predicate bits -> __ballot -> scalar ctz
// loop. Hit j is wave-uniform: broadcast dv[j]/h[j] loads, uniform (m,l),
// lane (c = lane&15) owns accumulator channel c (2 FMA/hit).
// ---------------------------------------------------------------------------
__global__ __launch_bounds__(256) void hat_attn(
    const float* __restrict__ h, const float* __restrict__ s,
    const float* __restrict__ dv, const unsigned char* __restrict__ adj,
    const int* __restrict__ flag, float* __restrict__ out)
{
    const int lane = threadIdx.x & 63;
    const int row  = (blockIdx.x << 2) + (threadIdx.x >> 6);
    const int cc   = lane & 15;

    const float si = s[row];
    float m = -3.0e38f, l = 0.0f, acc = 0.0f;

    auto hit = [&](int j) {
        float e = si + dv[j];
        e = (e > 0.0f) ? e : ALPHA * e;               // LeakyReLU
        float hv = h[(size_t)j * CLS + cc];           // 64B broadcast line
        if (e <= m) {                                  // common path: 1 exp
            float w = __expf(e - m);
            l += w;
            acc = fmaf(w, hv, acc);
        } else {                                       // new max: rescale
            float sc = __expf(m - e);                  // exp(-inf)=0 on 1st
            l   = fmaf(l, sc, 1.0f);                   // w = exp(0) = 1
            acc = fmaf(acc, sc, hv);
            m = e;
        }
    };

    if (*flag) {
        // ---- byte-bool: lane loads 16 bytes; bit0-gather trick needs only
        // odd "true" bytes (numpy bool = 1; 255 also works). ----
        const uint4* arow = reinterpret_cast<const uint4*>(adj + (size_t)row * NN);
        #pragma unroll
        for (int it = 0; it < 8; ++it) {
            const uint4 a = arow[(it << 6) | lane];
            const int S = it << 10;                   // 1024 cols / iter
            // nibble per dword: bit k = (byte k & 1)
            unsigned n0 = ((a.x & 0x01010101u) * 0x01020408u) >> 24;
            unsigned n1 = ((a.y & 0x01010101u) * 0x01020408u) >> 24;
            unsigned n2 = ((a.z & 0x01010101u) * 0x01020408u) >> 24;
            unsigned n3 = ((a.w & 0x01010101u) * 0x01020408u) >> 24;
            unsigned pm = (n0 & 0xF) | ((n1 & 0xF) << 4)
                        | ((n2 & 0xF) << 8) | ((n3 & 0xF) << 12);
            #pragma unroll
            for (int k = 0; k < 16; ++k) {
                unsigned long long bmask = __ballot((pm >> k) & 1u);
                while (bmask) {
                    const int t = __builtin_ctzll(bmask);
                    bmask &= bmask - 1;
                    hit(S + (t << 4) + k);            // j = S + 16*t + k
                }
            }
        }
    } else {
        // ---- int32 0/1: lane loads 4 ints ----
        const uint4* arow = reinterpret_cast<const uint4*>(
            reinterpret_cast<const unsigned int*>(adj) + (size_t)row * NN);
        for (int it = 0; it < 32; ++it) {
            const uint4 a = arow[(it << 6) | lane];
            const int S = it << 8;                    // 256 cols / iter
            #pragma unroll
            for (int k = 0; k < 4; ++k) {
                const unsigned v = (&a.x)[k];
                unsigned long long bmask = __ballot(v != 0u);
                while (bmask) {
                    const int t = __builtin_ctzll(bmask);
                    bmask &= bmask - 1;
                    hit(S + (t << 2) + k);            // j = S + 4*t + k
                }
            }
        }
    }

    // epilogue: (m,l) uniform; acc channel cc lives in this lane.
    float* orow = out + (size_t)row * CLS;
    if (l > 0.0f) {
        float u = acc / l;
        u = (u > 0.0f) ? u : expm1f(u);               // elu
        float nsq = u * u;                            // 16-wide group reduce
        #pragma unroll
        for (int o = 8; o > 0; o >>= 1) nsq += __shfl_xor(nsq, o);
        float norm = fmaxf(sqrtf(nsq), 1e-15f);
        float th   = tanhf(norm);
        float sc2  = th / norm;                        // expmap0 scale
        const float maxnorm = 1.0f - 1e-5f;            // proj (c=1)
        float sc3  = (th > maxnorm) ? (maxnorm / th) : 1.0f;
        if (lane < CLS) orow[lane] = u * sc2 * sc3;   // coalesced 64B store
    } else {
        if (lane < CLS) orow[lane] = 0.0f;
    }
}

// ---------------------------------------------------------------------------
extern "C" void kernel_launch(void* const* d_in, const int* in_sizes, int n_in,
                              void* d_out, int out_size, void* d_ws, size_t ws_size,
                              hipStream_t stream) {
    const float*         x     = (const float*)d_in[0];
    const unsigned char* adj   = (const unsigned char*)d_in[1];
    const float*         W     = (const float*)d_in[2];
    const float*         b     = (const float*)d_in[3];
    const float*         a_src = (const float*)d_in[4];
    const float*         a_dst = (const float*)d_in[5];
    float*               out   = (float*)d_out;

    float* h    = (float*)d_ws;               // [NN, CLS]
    float* s    = h + (size_t)NN * CLS;       // [NN]
    float* dv   = s + NN;                     // [NN]
    int*   flag = (int*)(dv + NN);

    adj_probe<<<1, 64, 0, stream>>>(adj, flag);
    hat_feat<<<NN / 4, 256, 0, stream>>>(x, W, b, a_src, a_dst, h, s, dv);
    hat_attn<<<NN / 4, 256, 0, stream>>>(h, s, dv, adj, flag, out);
}